// Round 1
// baseline (154.704 us; speedup 1.0000x reference)
//
#include <hip/hip_runtime.h>

#define NB 4
#define NC 64
#define NH 256
#define NW 256
#define TH 32          // output rows per block
#define LR 38          // TH + 6 halo rows
#define LSTR 264       // LDS row stride in floats (global cols -4 .. 259)
#define NCHUNK 66      // float4 chunks per LDS row
#define CH_PER 4       // channels per block

__global__ __launch_bounds__(256, 2)
void adaptive_gauss7(const float* __restrict__ x,
                     const float* __restrict__ persp,
                     const float* __restrict__ alpha_p,
                     const float* __restrict__ beta_p,
                     const float* __restrict__ gamma_p,
                     float* __restrict__ out)
{
    __shared__ float xs[LR * LSTR];   // 40128 B

    const int tid  = threadIdx.x;
    const int lane = tid & 63;        // 64 lanes -> 64 column groups (4 cols each)
    const int trow = tid >> 6;        // 0..3 -> 8-row strip each
    const int h0   = blockIdx.x * TH;
    const int c0   = blockIdx.y * CH_PER;
    const int b    = blockIdx.z;
    const int colbase = lane * 4;     // output col base (global)
    const int rbase   = trow * 8;     // first output row (relative to h0)

    const float alpha = alpha_p[0];
    const float beta  = beta_p[0];
    const float gamma = gamma_p[0];

    // ---- phase A: per-pixel g = exp(-1/(2*sigma^2)), once per block ----
    float gw[8][4];
    {
        const float* pp = persp + (size_t)b * NH * NW;
        #pragma unroll
        for (int r = 0; r < 8; ++r) {
            const int h = h0 + rbase + r;
            const float4 p4v = *(const float4*)(pp + (size_t)h * NW + colbase);
            const float pv[4] = {p4v.x, p4v.y, p4v.z, p4v.w};
            #pragma unroll
            for (int k = 0; k < 4; ++k) {
                const float z  = fmaf(beta, pv[k], gamma);
                const float sg = __builtin_amdgcn_rcpf(1.0f + __expf(-z));
                const float sigma = fmaxf(alpha * sg, 1e-4f);
                const float t  = 0.5f * __builtin_amdgcn_rcpf(sigma * sigma);
                gw[r][k] = __expf(-t);   // g; weights are g^(d^2)
            }
        }
    }

    // ---- phase B: channel loop ----
    for (int ci = 0; ci < CH_PER; ++ci) {
        const int c = c0 + ci;
        const float* xp = x + (size_t)(b * NC + c) * NH * NW;

        __syncthreads();   // protect LDS from previous channel's readers
        // stage x tile: rows h0-3 .. h0+34, cols -4 .. 259 (zero-padded OOB)
        for (int idx = tid; idx < LR * NCHUNK; idx += 256) {
            const int r  = idx / NCHUNK;
            const int c4 = idx - r * NCHUNK;
            const int gr = h0 - 3 + r;
            const int gc = c4 * 4 - 4;
            float4 v = make_float4(0.f, 0.f, 0.f, 0.f);
            if ((unsigned)gr < NH && (unsigned)gc < NW)
                v = *(const float4*)(xp + (size_t)gr * NW + gc);
            *(float4*)(&xs[r * LSTR + c4 * 4]) = v;
        }
        __syncthreads();

        // sliding 7-row window in registers, 12 floats wide (cols colbase-4 .. +7)
        float win[7][12];
        #pragma unroll
        for (int i = 0; i < 7; ++i) {
            const float* src = &xs[(rbase + i) * LSTR + colbase];
            const float4 a0 = *(const float4*)(src);
            const float4 a1 = *(const float4*)(src + 4);
            const float4 a2 = *(const float4*)(src + 8);
            win[i][0] = a0.x; win[i][1] = a0.y; win[i][2]  = a0.z; win[i][3]  = a0.w;
            win[i][4] = a1.x; win[i][5] = a1.y; win[i][6]  = a1.z; win[i][7]  = a1.w;
            win[i][8] = a2.x; win[i][9] = a2.y; win[i][10] = a2.z; win[i][11] = a2.w;
        }

        float* outp = out + (size_t)(b * NC + c) * NH * NW
                          + (size_t)(h0 + rbase) * NW + colbase;

        #pragma unroll
        for (int orow = 0; orow < 8; ++orow) {
            if (orow > 0) {   // advance window: load LDS row rbase+orow+6
                const int wi = (orow + 6) % 7;
                const float* src = &xs[(rbase + orow + 6) * LSTR + colbase];
                const float4 a0 = *(const float4*)(src);
                const float4 a1 = *(const float4*)(src + 4);
                const float4 a2 = *(const float4*)(src + 8);
                win[wi][0] = a0.x; win[wi][1] = a0.y; win[wi][2]  = a0.z; win[wi][3]  = a0.w;
                win[wi][4] = a1.x; win[wi][5] = a1.y; win[wi][6]  = a1.z; win[wi][7]  = a1.w;
                win[wi][8] = a2.x; win[wi][9] = a2.y; win[wi][10] = a2.z; win[wi][11] = a2.w;
            }
            float res[4];
            #pragma unroll
            for (int k = 0; k < 4; ++k) {
                const float g  = gw[orow][k];
                const float g2 = g * g;
                const float p4 = g2 * g2;          // g^4
                const float p9 = p4 * p4 * g;      // g^9
                const float S  = fmaf(2.0f, (g + p4) + p9, 1.0f);
                const float inv  = __builtin_amdgcn_rcpf(S);
                const float inv2 = inv * inv;      // 1/S^2
                float rs[7];
                #pragma unroll
                for (int j = 0; j < 7; ++j) {
                    const int wr = (orow + j) % 7;   // window row holding LDS row rbase+orow+j
                    rs[j] = fmaf(p9, win[wr][k+1] + win[wr][k+7],
                            fmaf(p4, win[wr][k+2] + win[wr][k+6],
                            fmaf(g,  win[wr][k+3] + win[wr][k+5],
                                     win[wr][k+4])));
                }
                const float acc = fmaf(p9, rs[0] + rs[6],
                                  fmaf(p4, rs[1] + rs[5],
                                  fmaf(g,  rs[2] + rs[4],
                                           rs[3])));
                res[k] = acc * inv2;
            }
            *(float4*)(outp + (size_t)orow * NW) =
                make_float4(res[0], res[1], res[2], res[3]);
        }
    }
}

extern "C" void kernel_launch(void* const* d_in, const int* in_sizes, int n_in,
                              void* d_out, int out_size, void* d_ws, size_t ws_size,
                              hipStream_t stream) {
    const float* x     = (const float*)d_in[0];
    const float* persp = (const float*)d_in[1];
    const float* alpha = (const float*)d_in[2];
    const float* beta  = (const float*)d_in[3];
    const float* gamma = (const float*)d_in[4];
    float* outp        = (float*)d_out;
    // kernel_size (d_in[5]) is fixed at 7 per the reference setup
    dim3 grid(NH / TH, NC / CH_PER, NB);
    adaptive_gauss7<<<grid, dim3(256), 0, stream>>>(x, persp, alpha, beta, gamma, outp);
}